// Round 12
// baseline (145.834 us; speedup 1.0000x reference)
//
#include <hip/hip_runtime.h>
#include <float.h>

#define K_CODES 1024
#define DIM 64
#define BR 128
// Half-scale distances (ne/2 - sim, z pre-negated, norms pre-halved).
// bf16x3 half-scale error bound <= 7e-5 worst-case; gate 1.25e-4
// (== 2.5e-4 full-scale, measured ~113/65536 flagged rows in round 5).
#define SAFE_MARGIN_H 1.25e-4f

typedef __attribute__((ext_vector_type(8))) short bf16x8;
typedef __attribute__((ext_vector_type(8))) unsigned short u16x8;
typedef __attribute__((ext_vector_type(4))) float f32x4;

__device__ __forceinline__ unsigned short f2bf(float f) {
    unsigned int u = __float_as_uint(f);
    u += 0x7fff + ((u >> 16) & 1);          // round-to-nearest-even
    return (unsigned short)(u >> 16);
}
__device__ __forceinline__ float bf2f(unsigned short h) {
    return __uint_as_float(((unsigned int)h) << 16);
}
// XOR swizzle for 128-byte LDS rows (A-stage only), both write & read sides.
__device__ __forceinline__ int swz(int row, int byteInRow) {
    return row * 128 + (byteInRow ^ ((row & 7) << 4));
}

// ---------- prep: transpose E, bf16 hi/lo splits, norms, zero counter ----------
__global__ __launch_bounds__(256) void vq_prep2(
    const float* __restrict__ E, float* __restrict__ Et,
    unsigned short* __restrict__ Eh, unsigned short* __restrict__ El,
    float* __restrict__ nrm, float* __restrict__ nrm2, int* __restrict__ cnt)
{
    __shared__ float T[64 * 17];
    const int t = threadIdx.x;
    const int k0 = blockIdx.x * 16;
    if (blockIdx.x == 0 && t == 0) *cnt = 0;
    #pragma unroll
    for (int i = 0; i < 4; ++i) {
        int idx = i * 256 + t;
        int d = idx >> 4, kk = idx & 15;
        T[d * 17 + kk] = E[d * K_CODES + k0 + kk];
    }
    __syncthreads();
    #pragma unroll
    for (int i = 0; i < 4; ++i) {
        int idx = i * 256 + t;
        int kk = idx >> 6, d = idx & 63;
        float v = T[d * 17 + kk];
        Et[(size_t)(k0 + kk) * DIM + d] = v;
        unsigned short h = f2bf(v);
        Eh[(size_t)(k0 + kk) * DIM + d] = h;
        El[(size_t)(k0 + kk) * DIM + d] = f2bf(v - bf2f(h));
    }
    if (t < 16) {
        float s = 0.f;
        #pragma unroll
        for (int d = 0; d < DIM; ++d) {
            float v = T[d * 17 + t];
            s = __builtin_fmaf(v, v, s);
        }
        nrm [k0 + t] = s;
        nrm2[k0 + t] = 0.5f * s;    // exact (exponent decrement)
    }
}

// load B-fragments for code-group g straight from global (L2-resident tables);
// addresses provably identical to the former LDS-staged frag reads.
#define LOADG(BH0, BH1, BL0, BL1, NE, g) do {                              \
    int _c = (g) * 16 + col;                                               \
    const unsigned short* _pe = Eh + (size_t)_c * DIM + q * 8;             \
    const unsigned short* _pl = El + (size_t)_c * DIM + q * 8;             \
    BH0 = *(const bf16x8*)(_pe);                                           \
    BH1 = *(const bf16x8*)(_pe + 32);                                      \
    BL0 = *(const bf16x8*)(_pl);                                           \
    BL1 = *(const bf16x8*)(_pl + 32);                                      \
    NE  = nrm2[_c];                                                        \
} while (0)

// bf16x3 distances for group g + med3 top-2 update (proven epilogue order).
#define COMP(BH0, BH1, BL0, BL1, NE, g) do {                               \
    int _code = (g) * 16 + col;                                            \
    _Pragma("unroll")                                                      \
    for (int m = 0; m < 2; ++m) {                                          \
        f32x4 acc = {NE, NE, NE, NE};  /* C-in carries ne/2; A = -z */     \
        acc = __builtin_amdgcn_mfma_f32_16x16x32_bf16(aH[m][0], BH0, acc, 0,0,0); \
        acc = __builtin_amdgcn_mfma_f32_16x16x32_bf16(aH[m][1], BH1, acc, 0,0,0); \
        acc = __builtin_amdgcn_mfma_f32_16x16x32_bf16(aH[m][0], BL0, acc, 0,0,0); \
        acc = __builtin_amdgcn_mfma_f32_16x16x32_bf16(aH[m][1], BL1, acc, 0,0,0); \
        acc = __builtin_amdgcn_mfma_f32_16x16x32_bf16(aL[m][0], BH0, acc, 0,0,0); \
        acc = __builtin_amdgcn_mfma_f32_16x16x32_bf16(aL[m][1], BH1, acc, 0,0,0); \
        _Pragma("unroll")                                                  \
        for (int j = 0; j < 4; ++j) {                                      \
            float _d = acc[j];                                             \
            bool _lt = _d < b1[m][j];                                      \
            float _nb1 = fminf(b1[m][j], _d);                              \
            b2[m][j] = __builtin_amdgcn_fmed3f(b1[m][j], b2[m][j], _d);    \
            i1[m][j] = _lt ? _code : i1[m][j];                             \
            b1[m][j] = _nb1;                                               \
        }                                                                  \
    }                                                                      \
} while (0)

// ---------- main: barrier-free streaming; A staged once, B from L2 ----------
__global__ __launch_bounds__(256, 2) void vq_mfma(
    const float* __restrict__ x,
    const unsigned short* __restrict__ Eh,
    const unsigned short* __restrict__ El,
    const float* __restrict__ nrm2,
    const float* __restrict__ Et,
    float* __restrict__ out,
    int* __restrict__ cnt, int* __restrict__ list)
{
    __shared__ char lds[32768 + 512];
    char* Ah = lds;                      // 16 KB (A-stage, kept whole kernel)
    char* Al = lds + 16384;              // 16 KB
    int*  bidx = (int*)(lds + 32768);    // 128 winners

    const int t    = threadIdx.x;
    const int lane = t & 63;
    const int wv   = t >> 6;
    const int col  = lane & 15;
    const int q    = lane >> 4;
    const int koff = q * 16;
    const long r0  = (long)blockIdx.x * BR;

    // ---- stage A: 128 rows, NEGATED fp32 -> bf16 hi/lo, swizzled (proven) ----
    {
        int row = t >> 1, h = t & 1;
        const float4* src = (const float4*)(x + (r0 + row) * DIM + h * 32);
        float v[32];
        #pragma unroll
        for (int i = 0; i < 8; ++i) {
            float4 f = src[i];
            v[4*i+0] = -f.x; v[4*i+1] = -f.y; v[4*i+2] = -f.z; v[4*i+3] = -f.w;
        }
        unsigned short hi[32], lo[32];
        #pragma unroll
        for (int i = 0; i < 32; ++i) {
            hi[i] = f2bf(v[i]);
            lo[i] = f2bf(v[i] - bf2f(hi[i]));
        }
        #pragma unroll
        for (int s = 0; s < 2; ++s) {
            int seg = h * 2 + s;
            *(u16x8*)(Ah + swz(row, seg*32))      = *(u16x8*)(hi + s*16);
            *(u16x8*)(Ah + swz(row, seg*32 + 16)) = *(u16x8*)(hi + s*16 + 8);
            *(u16x8*)(Al + swz(row, seg*32))      = *(u16x8*)(lo + s*16);
            *(u16x8*)(Al + swz(row, seg*32 + 16)) = *(u16x8*)(lo + s*16 + 8);
        }
    }
    __syncthreads();

    // ---- A fragments (-z): A[row=lane&15][k=(lane>>4)*8+j], 2 m-tiles/wave ----
    bf16x8 aH[2][2], aL[2][2];
    #pragma unroll
    for (int m = 0; m < 2; ++m) {
        int arow = wv * 32 + m * 16 + col;
        #pragma unroll
        for (int kk = 0; kk < 2; ++kk) {
            aH[m][kk] = *(bf16x8*)(Ah + swz(arow, kk*64 + koff));
            aL[m][kk] = *(bf16x8*)(Al + swz(arow, kk*64 + koff));
        }
    }
    // NO barrier: A region is not reused; main loop touches no LDS.

    float b1[2][4], b2[2][4];
    int   i1[2][4];
    #pragma unroll
    for (int m = 0; m < 2; ++m)
        #pragma unroll
        for (int j = 0; j < 4; ++j) { b1[m][j] = FLT_MAX; b2[m][j] = FLT_MAX; i1[m][j] = 0x7fffffff; }

    // ---- barrier-free main loop: 4-deep named prefetch ring over 64 groups ----
    bf16x8 p0h0, p0h1, p0l0, p0l1;  float p0n;
    bf16x8 p1h0, p1h1, p1l0, p1l1;  float p1n;
    bf16x8 p2h0, p2h1, p2l0, p2l1;  float p2n;
    bf16x8 p3h0, p3h1, p3l0, p3l1;  float p3n;
    LOADG(p0h0, p0h1, p0l0, p0l1, p0n, 0);
    LOADG(p1h0, p1h1, p1l0, p1l1, p1n, 1);
    LOADG(p2h0, p2h1, p2l0, p2l1, p2n, 2);
    LOADG(p3h0, p3h1, p3l0, p3l1, p3n, 3);
    #pragma unroll 1
    for (int nt = 0; nt < 64; nt += 4) {
        COMP (p0h0, p0h1, p0l0, p0l1, p0n, nt);
        LOADG(p0h0, p0h1, p0l0, p0l1, p0n, (nt + 4) & 63);   // wrap: branchless tail
        COMP (p1h0, p1h1, p1l0, p1l1, p1n, nt + 1);
        LOADG(p1h0, p1h1, p1l0, p1l1, p1n, (nt + 5) & 63);
        COMP (p2h0, p2h1, p2l0, p2l1, p2n, nt + 2);
        LOADG(p2h0, p2h1, p2l0, p2l1, p2n, (nt + 6) & 63);
        COMP (p3h0, p3h1, p3l0, p3l1, p3n, nt + 3);
        LOADG(p3h0, p3h1, p3l0, p3l1, p3n, (nt + 7) & 63);
    }

    // ---- top-2 merge across the 16 lanes holding each row ----
    #pragma unroll
    for (int msk = 1; msk < 16; msk <<= 1) {
        #pragma unroll
        for (int m = 0; m < 2; ++m)
            #pragma unroll
            for (int j = 0; j < 4; ++j) {
                float o1 = __shfl_xor(b1[m][j], msk, 64);
                int   oi = __shfl_xor(i1[m][j], msk, 64);
                float o2 = __shfl_xor(b2[m][j], msk, 64);
                bool take = (o1 < b1[m][j]) || (o1 == b1[m][j] && oi < i1[m][j]);
                float worst = take ? b1[m][j] : o1;
                if (take) { b1[m][j] = o1; i1[m][j] = oi; }
                b2[m][j] = fminf(fminf(b2[m][j], o2), worst);
            }
    }
    if (col == 0) {
        #pragma unroll
        for (int m = 0; m < 2; ++m)
            #pragma unroll
            for (int j = 0; j < 4; ++j) {
                int rowl = wv * 32 + m * 16 + q * 4 + j;   // C/D: row=(lane>>4)*4+reg
                bidx[rowl] = i1[m][j];
                if (b2[m][j] - b1[m][j] <= SAFE_MARGIN_H) {
                    int p = atomicAdd(cnt, 1);             // global, rare (~113)
                    list[p] = (int)(r0 + rowl);
                }
            }
    }
    __syncthreads();

    // ---- fused gather: bit-exact embedding rows ----
    {
        int rowl = t >> 1, h = t & 1;
        int code = bidx[rowl];
        const float4* src = (const float4*)(Et + (size_t)code * DIM + h * 32);
        float4* dst = (float4*)(out + (size_t)(r0 + rowl) * DIM + h * 32);
        #pragma unroll
        for (int i = 0; i < 8; ++i) dst[i] = src[i];
    }
}

// ---------- refine: exact fp32 re-solve, one BLOCK per flagged row ----------
// Proven arithmetic (absmax 0.0 rounds 6/7/9/11): sequential-d fmaf chains,
// fmaf(-2, acc, zn + nrm); 4 codes/thread, coalesced native-E reads.
__global__ __launch_bounds__(256) void vq_refine3(
    const float* __restrict__ x, const float* __restrict__ E,
    const float* __restrict__ Et, const float* __restrict__ nrm,
    float* __restrict__ out,
    const int* __restrict__ cnt, const int* __restrict__ list)
{
    __shared__ float zsh[DIM];
    __shared__ float rv[4];
    __shared__ int   ri[4];
    __shared__ int   winner;
    const int n = *cnt;
    const int t = threadIdx.x;
    const int lane = t & 63, wv = t >> 6;

    for (int i = blockIdx.x; i < n; i += gridDim.x) {
        int row = list[i];
        if (t < DIM) zsh[t] = x[(size_t)row * DIM + t];
        __syncthreads();
        float zn = 0.f;
        #pragma unroll
        for (int d = 0; d < DIM; ++d) zn = __builtin_fmaf(zsh[d], zsh[d], zn);
        float a0 = 0.f, a1 = 0.f, a2 = 0.f, a3 = 0.f;
        #pragma unroll
        for (int d = 0; d < DIM; ++d) {
            float zd = zsh[d];
            const float* Ed = E + d * K_CODES;
            a0 = __builtin_fmaf(zd, Ed[t      ], a0);
            a1 = __builtin_fmaf(zd, Ed[t + 256], a1);
            a2 = __builtin_fmaf(zd, Ed[t + 512], a2);
            a3 = __builtin_fmaf(zd, Ed[t + 768], a3);
        }
        float d0 = __builtin_fmaf(-2.f, a0, zn + nrm[t      ]);
        float d1 = __builtin_fmaf(-2.f, a1, zn + nrm[t + 256]);
        float d2 = __builtin_fmaf(-2.f, a2, zn + nrm[t + 512]);
        float d3 = __builtin_fmaf(-2.f, a3, zn + nrm[t + 768]);
        float bv = d0; int bi = t;                       // ascending, strict <
        if (d1 < bv) { bv = d1; bi = t + 256; }
        if (d2 < bv) { bv = d2; bi = t + 512; }
        if (d3 < bv) { bv = d3; bi = t + 768; }
        #pragma unroll
        for (int m = 1; m < 64; m <<= 1) {
            float ov = __shfl_xor(bv, m, 64);
            int   oi = __shfl_xor(bi, m, 64);
            if (ov < bv || (ov == bv && oi < bi)) { bv = ov; bi = oi; }
        }
        if (lane == 0) { rv[wv] = bv; ri[wv] = bi; }
        __syncthreads();
        if (t == 0) {
            float v = rv[0]; int b = ri[0];
            #pragma unroll
            for (int w = 1; w < 4; ++w)
                if (rv[w] < v || (rv[w] == v && ri[w] < b)) { v = rv[w]; b = ri[w]; }
            winner = b;
        }
        __syncthreads();
        if (t < DIM) out[(size_t)row * DIM + t] = Et[(size_t)winner * DIM + t];
        __syncthreads();                                 // before zsh reuse
    }
}

extern "C" void kernel_launch(void* const* d_in, const int* in_sizes, int n_in,
                              void* d_out, int out_size, void* d_ws, size_t ws_size,
                              hipStream_t stream) {
    const float* x = (const float*)d_in[0];
    const float* E = (const float*)d_in[1];
    float* out = (float*)d_out;

    char* ws = (char*)d_ws;
    float*          Et   = (float*)ws;                        // 256 KiB
    unsigned short* Eh   = (unsigned short*)(ws + 262144);    // 128 KiB
    unsigned short* El   = (unsigned short*)(ws + 393216);    // 128 KiB
    float*          nrm  = (float*)(ws + 524288);             // 4 KiB
    float*          nrm2 = (float*)(ws + 528384);             // 4 KiB
    int*            cnt  = (int*)(ws + 532480);               // 4 B
    int*            list = (int*)(ws + 532736);               // 256 KiB

    int nrows = in_sizes[0] / DIM;                            // 65536

    vq_prep2<<<64, 256, 0, stream>>>(E, Et, Eh, El, nrm, nrm2, cnt);
    vq_mfma<<<nrows / BR, 256, 0, stream>>>(x, Eh, El, nrm2, Et, out, cnt, list);
    vq_refine3<<<512, 256, 0, stream>>>(x, E, Et, nrm, out, cnt, list);
}

// Round 13
// 124.364 us; speedup vs baseline: 1.1726x; 1.1726x over previous
//
#include <hip/hip_runtime.h>
#include <float.h>

#define K_CODES 1024
#define DIM 64
#define BR 128
// Half-scale distances (ne/2 - sim, z pre-negated, norms pre-halved).
// bf16x3 half-scale error bound <= 7e-5 worst-case; gate 1.25e-4
// (== 2.5e-4 full-scale, measured ~113/65536 flagged rows in round 5).
#define SAFE_MARGIN_H 1.25e-4f

typedef __attribute__((ext_vector_type(8))) short bf16x8;
typedef __attribute__((ext_vector_type(8))) unsigned short u16x8;
typedef __attribute__((ext_vector_type(4))) float f32x4;

__device__ __forceinline__ unsigned short f2bf(float f) {
    unsigned int u = __float_as_uint(f);
    u += 0x7fff + ((u >> 16) & 1);          // round-to-nearest-even
    return (unsigned short)(u >> 16);
}
__device__ __forceinline__ float bf2f(unsigned short h) {
    return __uint_as_float(((unsigned int)h) << 16);
}
// XOR swizzle for 128-byte LDS rows (A-stage only), both write & read sides.
__device__ __forceinline__ int swz(int row, int byteInRow) {
    return row * 128 + (byteInRow ^ ((row & 7) << 4));
}

// ---------- prep: transpose E, PERMUTED bf16 hi/lo frag tables, norms ----------
// Ehp/Elp layout: fragment (code-tile ct, k-frag kf) is 1 KB holding lane
// l = q*16+col -> element (code = ct*16+col, d = kf*32 + q*8 + j). A wave's
// B-frag load is then ONE coalesced 1 KB transaction (round-12 fix).
__global__ __launch_bounds__(256) void vq_prep2(
    const float* __restrict__ E, float* __restrict__ Et,
    unsigned short* __restrict__ Ehp, unsigned short* __restrict__ Elp,
    float* __restrict__ nrm, float* __restrict__ nrm2, int* __restrict__ cnt)
{
    __shared__ float T[64 * 17];
    const int t = threadIdx.x;
    const int k0 = blockIdx.x * 16;
    if (blockIdx.x == 0 && t == 0) *cnt = 0;
    #pragma unroll
    for (int i = 0; i < 4; ++i) {
        int idx = i * 256 + t;
        int d = idx >> 4, kk = idx & 15;
        T[d * 17 + kk] = E[d * K_CODES + k0 + kk];
    }
    __syncthreads();
    #pragma unroll
    for (int i = 0; i < 4; ++i) {
        int idx = i * 256 + t;
        int kk = idx >> 6, d = idx & 63;
        int code = k0 + kk;
        float v = T[d * 17 + kk];
        Et[(size_t)code * DIM + d] = v;
        unsigned short h = f2bf(v);
        unsigned short l = f2bf(v - bf2f(h));
        int ct = code >> 4, col = code & 15;
        int kf = d >> 5, q = (d >> 3) & 3, j = d & 7;
        size_t pidx = (size_t)(ct * 2 + kf) * 512 + q * 128 + col * 8 + j;
        Ehp[pidx] = h;
        Elp[pidx] = l;
    }
    if (t < 16) {
        float s = 0.f;
        #pragma unroll
        for (int d = 0; d < DIM; ++d) {
            float v = T[d * 17 + t];
            s = __builtin_fmaf(v, v, s);
        }
        nrm [k0 + t] = s;
        nrm2[k0 + t] = 0.5f * s;    // exact (exponent decrement)
    }
}

// coalesced B-frag load for code-group g: 4 x 1KB wave transactions + norm.
#define LOADG(BH0, BH1, BL0, BL1, NE, g) do {                              \
    const unsigned short* _ph = Ehp + (size_t)(g) * 1024 + lane * 8;       \
    const unsigned short* _pl = Elp + (size_t)(g) * 1024 + lane * 8;       \
    BH0 = *(const bf16x8*)(_ph);                                           \
    BH1 = *(const bf16x8*)(_ph + 512);                                     \
    BL0 = *(const bf16x8*)(_pl);                                           \
    BL1 = *(const bf16x8*)(_pl + 512);                                     \
    NE  = nrm2[(g) * 16 + col];                                            \
} while (0)

// bf16x3 distances for group g + med3 top-2 update (proven epilogue order).
#define COMP(BH0, BH1, BL0, BL1, NE, g) do {                               \
    int _code = (g) * 16 + col;                                            \
    _Pragma("unroll")                                                      \
    for (int m = 0; m < 2; ++m) {                                          \
        f32x4 acc = {NE, NE, NE, NE};  /* C-in carries ne/2; A = -z */     \
        acc = __builtin_amdgcn_mfma_f32_16x16x32_bf16(aH[m][0], BH0, acc, 0,0,0); \
        acc = __builtin_amdgcn_mfma_f32_16x16x32_bf16(aH[m][1], BH1, acc, 0,0,0); \
        acc = __builtin_amdgcn_mfma_f32_16x16x32_bf16(aH[m][0], BL0, acc, 0,0,0); \
        acc = __builtin_amdgcn_mfma_f32_16x16x32_bf16(aH[m][1], BL1, acc, 0,0,0); \
        acc = __builtin_amdgcn_mfma_f32_16x16x32_bf16(aL[m][0], BH0, acc, 0,0,0); \
        acc = __builtin_amdgcn_mfma_f32_16x16x32_bf16(aL[m][1], BH1, acc, 0,0,0); \
        _Pragma("unroll")                                                  \
        for (int j = 0; j < 4; ++j) {                                      \
            float _d = acc[j];                                             \
            bool _lt = _d < b1[m][j];                                      \
            float _nb1 = fminf(b1[m][j], _d);                              \
            b2[m][j] = __builtin_amdgcn_fmed3f(b1[m][j], b2[m][j], _d);    \
            i1[m][j] = _lt ? _code : i1[m][j];                             \
            b1[m][j] = _nb1;                                               \
        }                                                                  \
    }                                                                      \
} while (0)

// ---------- main: barrier-free streaming; A staged once, B coalesced from L1/L2 ----------
// launch_bounds (256,1): full VGPR budget so the 4-deep ring stays LIVE
// (round 12: (256,2) heuristic collapsed it to 80 VGPR and serialized loads).
__global__ __launch_bounds__(256, 1) void vq_mfma(
    const float* __restrict__ x,
    const unsigned short* __restrict__ Ehp,
    const unsigned short* __restrict__ Elp,
    const float* __restrict__ nrm2,
    const float* __restrict__ Et,
    float* __restrict__ out,
    int* __restrict__ cnt, int* __restrict__ list)
{
    __shared__ char lds[32768 + 512];
    char* Ah = lds;                      // 16 KB (A-stage, kept whole kernel)
    char* Al = lds + 16384;              // 16 KB
    int*  bidx = (int*)(lds + 32768);    // 128 winners

    const int t    = threadIdx.x;
    const int lane = t & 63;
    const int wv   = t >> 6;
    const int col  = lane & 15;
    const int q    = lane >> 4;
    const int koff = q * 16;
    const long r0  = (long)blockIdx.x * BR;

    // ---- stage A: 128 rows, NEGATED fp32 -> bf16 hi/lo, swizzled (proven) ----
    {
        int row = t >> 1, h = t & 1;
        const float4* src = (const float4*)(x + (r0 + row) * DIM + h * 32);
        float v[32];
        #pragma unroll
        for (int i = 0; i < 8; ++i) {
            float4 f = src[i];
            v[4*i+0] = -f.x; v[4*i+1] = -f.y; v[4*i+2] = -f.z; v[4*i+3] = -f.w;
        }
        unsigned short hi[32], lo[32];
        #pragma unroll
        for (int i = 0; i < 32; ++i) {
            hi[i] = f2bf(v[i]);
            lo[i] = f2bf(v[i] - bf2f(hi[i]));
        }
        #pragma unroll
        for (int s = 0; s < 2; ++s) {
            int seg = h * 2 + s;
            *(u16x8*)(Ah + swz(row, seg*32))      = *(u16x8*)(hi + s*16);
            *(u16x8*)(Ah + swz(row, seg*32 + 16)) = *(u16x8*)(hi + s*16 + 8);
            *(u16x8*)(Al + swz(row, seg*32))      = *(u16x8*)(lo + s*16);
            *(u16x8*)(Al + swz(row, seg*32 + 16)) = *(u16x8*)(lo + s*16 + 8);
        }
    }
    __syncthreads();

    // ---- A fragments (-z): A[row=lane&15][k=(lane>>4)*8+j], 2 m-tiles/wave ----
    bf16x8 aH[2][2], aL[2][2];
    #pragma unroll
    for (int m = 0; m < 2; ++m) {
        int arow = wv * 32 + m * 16 + col;
        #pragma unroll
        for (int kk = 0; kk < 2; ++kk) {
            aH[m][kk] = *(bf16x8*)(Ah + swz(arow, kk*64 + koff));
            aL[m][kk] = *(bf16x8*)(Al + swz(arow, kk*64 + koff));
        }
    }
    // NO barrier: A region is not reused; main loop touches no LDS.

    float b1[2][4], b2[2][4];
    int   i1[2][4];
    #pragma unroll
    for (int m = 0; m < 2; ++m)
        #pragma unroll
        for (int j = 0; j < 4; ++j) { b1[m][j] = FLT_MAX; b2[m][j] = FLT_MAX; i1[m][j] = 0x7fffffff; }

    // ---- barrier-free main loop: 4-deep named prefetch ring over 64 groups ----
    bf16x8 p0h0, p0h1, p0l0, p0l1;  float p0n;
    bf16x8 p1h0, p1h1, p1l0, p1l1;  float p1n;
    bf16x8 p2h0, p2h1, p2l0, p2l1;  float p2n;
    bf16x8 p3h0, p3h1, p3l0, p3l1;  float p3n;
    LOADG(p0h0, p0h1, p0l0, p0l1, p0n, 0);
    LOADG(p1h0, p1h1, p1l0, p1l1, p1n, 1);
    LOADG(p2h0, p2h1, p2l0, p2l1, p2n, 2);
    LOADG(p3h0, p3h1, p3l0, p3l1, p3n, 3);
    #pragma unroll 1
    for (int nt = 0; nt < 64; nt += 4) {
        COMP (p0h0, p0h1, p0l0, p0l1, p0n, nt);
        LOADG(p0h0, p0h1, p0l0, p0l1, p0n, (nt + 4) & 63);   // wrap: branchless tail
        COMP (p1h0, p1h1, p1l0, p1l1, p1n, nt + 1);
        LOADG(p1h0, p1h1, p1l0, p1l1, p1n, (nt + 5) & 63);
        COMP (p2h0, p2h1, p2l0, p2l1, p2n, nt + 2);
        LOADG(p2h0, p2h1, p2l0, p2l1, p2n, (nt + 6) & 63);
        COMP (p3h0, p3h1, p3l0, p3l1, p3n, nt + 3);
        LOADG(p3h0, p3h1, p3l0, p3l1, p3n, (nt + 7) & 63);
    }

    // ---- top-2 merge across the 16 lanes holding each row ----
    #pragma unroll
    for (int msk = 1; msk < 16; msk <<= 1) {
        #pragma unroll
        for (int m = 0; m < 2; ++m)
            #pragma unroll
            for (int j = 0; j < 4; ++j) {
                float o1 = __shfl_xor(b1[m][j], msk, 64);
                int   oi = __shfl_xor(i1[m][j], msk, 64);
                float o2 = __shfl_xor(b2[m][j], msk, 64);
                bool take = (o1 < b1[m][j]) || (o1 == b1[m][j] && oi < i1[m][j]);
                float worst = take ? b1[m][j] : o1;
                if (take) { b1[m][j] = o1; i1[m][j] = oi; }
                b2[m][j] = fminf(fminf(b2[m][j], o2), worst);
            }
    }
    if (col == 0) {
        #pragma unroll
        for (int m = 0; m < 2; ++m)
            #pragma unroll
            for (int j = 0; j < 4; ++j) {
                int rowl = wv * 32 + m * 16 + q * 4 + j;   // C/D: row=(lane>>4)*4+reg
                bidx[rowl] = i1[m][j];
                if (b2[m][j] - b1[m][j] <= SAFE_MARGIN_H) {
                    int p = atomicAdd(cnt, 1);             // global, rare (~113)
                    list[p] = (int)(r0 + rowl);
                }
            }
    }
    __syncthreads();

    // ---- fused gather: bit-exact embedding rows ----
    {
        int rowl = t >> 1, h = t & 1;
        int code = bidx[rowl];
        const float4* src = (const float4*)(Et + (size_t)code * DIM + h * 32);
        float4* dst = (float4*)(out + (size_t)(r0 + rowl) * DIM + h * 32);
        #pragma unroll
        for (int i = 0; i < 8; ++i) dst[i] = src[i];
    }
}

// ---------- refine: exact fp32 re-solve, one BLOCK per flagged row ----------
// Proven arithmetic (absmax 0.0 rounds 6/7/9/11/12): sequential-d fmaf chains,
// fmaf(-2, acc, zn + nrm); 4 codes/thread, coalesced native-E reads.
__global__ __launch_bounds__(256) void vq_refine3(
    const float* __restrict__ x, const float* __restrict__ E,
    const float* __restrict__ Et, const float* __restrict__ nrm,
    float* __restrict__ out,
    const int* __restrict__ cnt, const int* __restrict__ list)
{
    __shared__ float zsh[DIM];
    __shared__ float rv[4];
    __shared__ int   ri[4];
    __shared__ int   winner;
    const int n = *cnt;
    const int t = threadIdx.x;
    const int lane = t & 63, wv = t >> 6;

    for (int i = blockIdx.x; i < n; i += gridDim.x) {
        int row = list[i];
        if (t < DIM) zsh[t] = x[(size_t)row * DIM + t];
        __syncthreads();
        float zn = 0.f;
        #pragma unroll
        for (int d = 0; d < DIM; ++d) zn = __builtin_fmaf(zsh[d], zsh[d], zn);
        float a0 = 0.f, a1 = 0.f, a2 = 0.f, a3 = 0.f;
        #pragma unroll
        for (int d = 0; d < DIM; ++d) {
            float zd = zsh[d];
            const float* Ed = E + d * K_CODES;
            a0 = __builtin_fmaf(zd, Ed[t      ], a0);
            a1 = __builtin_fmaf(zd, Ed[t + 256], a1);
            a2 = __builtin_fmaf(zd, Ed[t + 512], a2);
            a3 = __builtin_fmaf(zd, Ed[t + 768], a3);
        }
        float d0 = __builtin_fmaf(-2.f, a0, zn + nrm[t      ]);
        float d1 = __builtin_fmaf(-2.f, a1, zn + nrm[t + 256]);
        float d2 = __builtin_fmaf(-2.f, a2, zn + nrm[t + 512]);
        float d3 = __builtin_fmaf(-2.f, a3, zn + nrm[t + 768]);
        float bv = d0; int bi = t;                       // ascending, strict <
        if (d1 < bv) { bv = d1; bi = t + 256; }
        if (d2 < bv) { bv = d2; bi = t + 512; }
        if (d3 < bv) { bv = d3; bi = t + 768; }
        #pragma unroll
        for (int m = 1; m < 64; m <<= 1) {
            float ov = __shfl_xor(bv, m, 64);
            int   oi = __shfl_xor(bi, m, 64);
            if (ov < bv || (ov == bv && oi < bi)) { bv = ov; bi = oi; }
        }
        if (lane == 0) { rv[wv] = bv; ri[wv] = bi; }
        __syncthreads();
        if (t == 0) {
            float v = rv[0]; int b = ri[0];
            #pragma unroll
            for (int w = 1; w < 4; ++w)
                if (rv[w] < v || (rv[w] == v && ri[w] < b)) { v = rv[w]; b = ri[w]; }
            winner = b;
        }
        __syncthreads();
        if (t < DIM) out[(size_t)row * DIM + t] = Et[(size_t)winner * DIM + t];
        __syncthreads();                                 // before zsh reuse
    }
}

extern "C" void kernel_launch(void* const* d_in, const int* in_sizes, int n_in,
                              void* d_out, int out_size, void* d_ws, size_t ws_size,
                              hipStream_t stream) {
    const float* x = (const float*)d_in[0];
    const float* E = (const float*)d_in[1];
    float* out = (float*)d_out;

    char* ws = (char*)d_ws;
    float*          Et   = (float*)ws;                        // 256 KiB
    unsigned short* Ehp  = (unsigned short*)(ws + 262144);    // 128 KiB (permuted)
    unsigned short* Elp  = (unsigned short*)(ws + 393216);    // 128 KiB (permuted)
    float*          nrm  = (float*)(ws + 524288);             // 4 KiB
    float*          nrm2 = (float*)(ws + 528384);             // 4 KiB
    int*            cnt  = (int*)(ws + 532480);               // 4 B
    int*            list = (int*)(ws + 532736);               // 256 KiB

    int nrows = in_sizes[0] / DIM;                            // 65536

    vq_prep2<<<64, 256, 0, stream>>>(E, Et, Ehp, Elp, nrm, nrm2, cnt);
    vq_mfma<<<nrows / BR, 256, 0, stream>>>(x, Ehp, Elp, nrm2, Et, out, cnt, list);
    vq_refine3<<<512, 256, 0, stream>>>(x, E, Et, nrm, out, cnt, list);
}